// Round 20
// baseline (373.672 us; speedup 1.0000x reference)
//
#include <hip/hip_runtime.h>
#include <stdint.h>

#define BATCH 8
#define NPTS  16384
#define BN    (BATCH * NPTS)
#define CH    256                 // points per LDS chunk (2 x 8 KB buffers)
#define NCH   (NPTS / CH)         // 64
#define QPB   256                 // 4 waves x 64 queries (2 query B-frags/wave)
#define MARGIN 4.0e-3f            // >= 2.6x worst-stack approx error (~1.5e-3)

typedef float f32x16 __attribute__((ext_vector_type(16)));
typedef short s16x8  __attribute__((ext_vector_type(8)));

__device__ __forceinline__ uint16_t bfr(float x) {
    uint32_t u = __float_as_uint(x);
    return (uint16_t)((u + 0x7FFFu + ((u >> 16) & 1u)) >> 16);
}
__device__ __forceinline__ float bff(uint16_t s) {
    return __uint_as_float(((uint32_t)s) << 16);
}
__device__ __forceinline__ void split2(float v, uint16_t* a, uint16_t* b) {
    *a = bfr(v); *b = bfr(v - bff(*a));
}
__device__ __forceinline__ uint32_t pk2(uint16_t lo, uint16_t hi) {
    return (uint32_t)lo | ((uint32_t)hi << 16);
}
// monotone f32 <-> u32 order map (handles negatives from cancellation)
__device__ __forceinline__ uint32_t key32(float d) {
    uint32_t b = __float_as_uint(d);
    return (b & 0x80000000u) ? ~b : (b | 0x80000000u);
}
__device__ __forceinline__ float dec32(uint32_t k) {
    return __uint_as_float((k & 0x80000000u) ? (k ^ 0x80000000u) : ~k);
}

#define F16(M_) M_(0) M_(1) M_(2) M_(3) M_(4) M_(5) M_(6) M_(7) \
                M_(8) M_(9) M_(10) M_(11) M_(12) M_(13) M_(14) M_(15)

#define MIN3(a, b, c) fminf(fminf((a), (b)), (c))

__device__ __forceinline__ float fold16(const f32x16 a) {
    const float u0 = MIN3(a[0],  a[1],  a[2]);
    const float u1 = MIN3(a[3],  a[4],  a[5]);
    const float u2 = MIN3(a[6],  a[7],  a[8]);
    const float u3 = MIN3(a[9],  a[10], a[11]);
    const float u4 = MIN3(a[12], a[13], a[14]);
    const float v0 = MIN3(u0, u1, a[15]);
    const float v1 = MIN3(u2, u3, u4);
    return fminf(v0, v1);
}

// ---- enc: per point, 16 bf16 slots = [1,1,Ya,Yb, H0,M0,H0,M0 | H1,M1,H1,M1, H2,M2,H2,M2]
__global__ __launch_bounds__(256) void enc_kernel(
    const float* __restrict__ Y, uint4* __restrict__ enc)
{
#pragma clang fp contract(off)
    const int g = blockIdx.x * 256 + threadIdx.x;     // 0..BN-1
    const int b = g >> 14, p = g & (NPTS - 1);
    const float y0 = Y[(size_t)g * 3 + 0];
    const float y1 = Y[(size_t)g * 3 + 1];
    const float y2 = Y[(size_t)g * 3 + 2];
    const float ys = (y0 * y0 + y1 * y1) + y2 * y2;   // np order (approx side)
    uint16_t Ya, Yb; split2(ys, &Ya, &Yb);
    uint16_t H0, M0; split2(-2.0f * y0, &H0, &M0);
    uint16_t H1, M1; split2(-2.0f * y1, &H1, &M1);
    uint16_t H2, M2; split2(-2.0f * y2, &H2, &M2);
    const uint16_t ONE = 0x3F80;
    const int ch = p >> 8, pp = p & (CH - 1);
    const size_t base = (size_t)(b * NCH + ch) * (2 * CH) + pp;
    enc[base]      = make_uint4(pk2(ONE, ONE), pk2(Ya, Yb), pk2(H0, M0), pk2(H0, M0));
    enc[base + CH] = make_uint4(pk2(H1, M1), pk2(H1, M1), pk2(H2, M2), pk2(H2, M2));
}

// decode (dir,batch,kh,xblk); ksplit=2: grid 2048, each block half the points
#define DECODE_DBX() \
    int dir, batch, kh, xblk; \
    { const int g = blockIdx.x; \
      const int s = 2 * (g & 7) + ((g >> 3) & 1); \
      dir = s >> 3; batch = s & 7; \
      if (ksplit == 2) { kh = (g >> 4) & 1; xblk = g >> 5; } \
      else             { kh = 0;            xblk = g >> 4; } }

#define STAGE(c, buf) { \
        const uint4* src_ = ep + (size_t)(c) * (2 * CH); \
        _Pragma("unroll") \
        for (int i_ = 0; i_ < 2; ++i_) \
            __builtin_amdgcn_global_load_lds( \
                (const __attribute__((address_space(1))) void*)(src_ + i_ * 256 + tid), \
                (__attribute__((address_space(3))) void*)&lds[buf][i_ * 256 + tid], \
                16, 0, 0); \
    }

#define MKQFR(dst, qq, qx0v, qx1v, qx2v, qxsv) { \
        const float* xp = Xp + (size_t)(bofs + (qq)) * 3; \
        qx0v = xp[0]; qx1v = xp[1]; qx2v = xp[2]; \
        qxsv = (qx0v * qx0v + qx1v * qx1v) + qx2v * qx2v; \
        uint16_t Xa, Xb; split2(qxsv, &Xa, &Xb); \
        uint16_t h0, m0; split2(qx0v, &h0, &m0); \
        uint16_t h1, m1; split2(qx1v, &h1, &m1); \
        uint16_t h2, m2; split2(qx2v, &h2, &m2); \
        const uint16_t ONE = 0x3F80; \
        if (hi == 0) { \
            dst[0]=(short)Xa; dst[1]=(short)Xb; dst[2]=(short)ONE; dst[3]=(short)ONE; \
            dst[4]=(short)h0; dst[5]=(short)h0; dst[6]=(short)m0;  dst[7]=(short)m0; \
        } else { \
            dst[0]=(short)h1; dst[1]=(short)h1; dst[2]=(short)m1;  dst[3]=(short)m1; \
            dst[4]=(short)h2; dst[5]=(short)h2; dst[6]=(short)m2;  dst[7]=(short)m2; \
        } }

// ============ sweep 1: per-query approx min -> mkey (u32 order keys) ============
// 2-acc structure: one point-tile per iteration (keeps unified VGPR+AGPR <= ~80
// so the HW can host 6 waves/SIMD; 4 live accs binned us at 4 waves -> 42% occ).
__global__ __launch_bounds__(256, 4) void nn_sweep1(
    const float* __restrict__ xyz1, const float* __restrict__ xyz2,
    const uint4* __restrict__ encA, const uint4* __restrict__ encB,
    uint32_t* __restrict__ mkey, int ksplit)
{
#pragma clang fp contract(off)
    __shared__ uint4 lds[2][2 * CH];                   // 2 x 8 KB

    const int tid = threadIdx.x;
    const int l   = tid & 63;
    const int wv  = tid >> 6;
    const int col = l & 31;
    const int hi  = l >> 5;
    DECODE_DBX()

    const float* Xp = dir ? xyz2 : xyz1;
    const uint4* ep = (dir ? encB : encA) + (size_t)batch * (NCH * 2 * CH);
    const int bofs  = batch * NPTS;
    const int qbase = xblk * QPB + wv * 64;
    const int chalf = NCH / ksplit;
    const int c0 = kh * chalf, c1 = c0 + chalf;

    const f32x16 zf = {0.f,0.f,0.f,0.f,0.f,0.f,0.f,0.f,
                       0.f,0.f,0.f,0.f,0.f,0.f,0.f,0.f};

    s16x8 qfr0, qfr1;
    float qa0, qa1, qa2, qas, qb0, qb1, qb2, qbs;
    MKQFR(qfr0, qbase + col,      qa0, qa1, qa2, qas)
    MKQFR(qfr1, qbase + 32 + col, qb0, qb1, qb2, qbs)
    (void)qa0; (void)qb0;

    const int ldsb = hi * CH + col;

    float run0 = __builtin_inff(), run1 = __builtin_inff();
    STAGE(c0, 0);
    __syncthreads();
    int cur = 0;
    for (int c = c0; c < c1; ++c) {
        if (c + 1 < c1) STAGE(c + 1, cur ^ 1);
#pragma unroll
        for (int tp = 0; tp < CH / 32; ++tp) {
            const s16x8 pA = *(const s16x8*)&lds[cur][ldsb + tp * 32];
            const f32x16 a0 = __builtin_amdgcn_mfma_f32_32x32x16_bf16(pA, qfr0, zf, 0, 0, 0);
            run0 = fminf(run0, fold16(a0));
            const f32x16 a1 = __builtin_amdgcn_mfma_f32_32x32x16_bf16(pA, qfr1, zf, 0, 0, 0);
            run1 = fminf(run1, fold16(a1));
        }
        __syncthreads();
        cur ^= 1;
    }
    run0 = fminf(run0, __shfl_xor(run0, 32, 64));
    run1 = fminf(run1, __shfl_xor(run1, 32, 64));
    if (l < 32) {
        uint32_t* mp = mkey + (size_t)dir * BN + bofs + qbase;
        atomicMin(&mp[col],      key32(run0));
        atomicMin(&mp[32 + col], key32(run1));
    }
}

// ====== sweep 2: candidates (approx d <= m'+MARGIN) + exact argmin ======
__global__ __launch_bounds__(256, 4) void nn_sweep2(
    const float* __restrict__ xyz1, const float* __restrict__ xyz2,
    const uint4* __restrict__ encA, const uint4* __restrict__ encB,
    const uint32_t* __restrict__ mkey, unsigned long long* __restrict__ gkeys,
    float* __restrict__ out, int ksplit)
{
#pragma clang fp contract(off)
    __shared__ uint4 lds[2][2 * CH];                   // 2 x 8 KB
    __shared__ unsigned long long keys[QPB];           // 2 KB

    const int tid = threadIdx.x;
    const int l   = tid & 63;
    const int wv  = tid >> 6;
    const int col = l & 31;
    const int hi  = l >> 5;
    DECODE_DBX()

    const float* Xp = dir ? xyz2 : xyz1;
    const float* Yp = dir ? xyz1 : xyz2;
    const uint4* ep = (dir ? encB : encA) + (size_t)batch * (NCH * 2 * CH);
    const int bofs  = batch * NPTS;
    const int qbase = xblk * QPB + wv * 64;
    const int chalf = NCH / ksplit;
    const int c0 = kh * chalf, c1 = c0 + chalf;

    keys[tid] = ~0ull;

    const f32x16 zf = {0.f,0.f,0.f,0.f,0.f,0.f,0.f,0.f,
                       0.f,0.f,0.f,0.f,0.f,0.f,0.f,0.f};

    // A-side (point) row calibration, packed 16 x 8 bits
    int rowpack[4] = {0, 0, 0, 0};
    {
        s16x8 pa = {0,0,0,0,0,0,0,0}, pb = {0,0,0,0,0,0,0,0};
        if (hi == 0) { pa[0] = (short)bfr((float)col); pb[0] = (short)0x3F80; }
        const f32x16 rowp = __builtin_amdgcn_mfma_f32_32x32x16_bf16(pa, pb, zf, 0, 0, 0);
#define PR(i) rowpack[(i) >> 2] |= ((int)rowp[i] & 0xFF) << (((i) & 3) * 8);
        F16(PR)
#undef PR
    }

    s16x8 qfr0, qfr1;
    float qa0, qa1, qa2, qas, qb0, qb1, qb2, qbs;
    MKQFR(qfr0, qbase + col,      qa0, qa1, qa2, qas)
    MKQFR(qfr1, qbase + 32 + col, qb0, qb1, qb2, qbs)

    float thr0, thr1;
    {
        const uint32_t* mp = mkey + (size_t)dir * BN + bofs + qbase;
        thr0 = dec32(mp[col]) + MARGIN;
        thr1 = dec32(mp[32 + col]) + MARGIN;
    }

    const int ldsb = hi * CH + col;

#define HITR(accv, jb, foff, thr, qx0, qx1, qx2, qxs, r) \
        if ((accv)[r] <= (thr)) { \
            const int jc = (jb) + ((rowpack[(r) >> 2] >> (((r) & 3) * 8)) & 0xFF); \
            const float* yq = Yp + (size_t)(bofs + jc) * 3; \
            const float py0 = yq[0], py1 = yq[1], py2 = yq[2]; \
            const float pys = (py0 * py0 + py1 * py1) + py2 * py2; \
            const float dd = ((qxs) - 2.0f * (((qx0) * py0 + (qx1) * py1) + (qx2) * py2)) + pys; \
            atomicMin(&keys[wv * 64 + (foff) + col], \
                      ((unsigned long long)key32(dd) << 32) | (uint32_t)jc); }
#define HIT(accv, jb, foff, thr, qx0, qx1, qx2, qxs) \
        if (fold16(accv) <= (thr)) { \
            HITR(accv, jb, foff, thr, qx0, qx1, qx2, qxs, 0) \
            HITR(accv, jb, foff, thr, qx0, qx1, qx2, qxs, 1) \
            HITR(accv, jb, foff, thr, qx0, qx1, qx2, qxs, 2) \
            HITR(accv, jb, foff, thr, qx0, qx1, qx2, qxs, 3) \
            HITR(accv, jb, foff, thr, qx0, qx1, qx2, qxs, 4) \
            HITR(accv, jb, foff, thr, qx0, qx1, qx2, qxs, 5) \
            HITR(accv, jb, foff, thr, qx0, qx1, qx2, qxs, 6) \
            HITR(accv, jb, foff, thr, qx0, qx1, qx2, qxs, 7) \
            HITR(accv, jb, foff, thr, qx0, qx1, qx2, qxs, 8) \
            HITR(accv, jb, foff, thr, qx0, qx1, qx2, qxs, 9) \
            HITR(accv, jb, foff, thr, qx0, qx1, qx2, qxs, 10) \
            HITR(accv, jb, foff, thr, qx0, qx1, qx2, qxs, 11) \
            HITR(accv, jb, foff, thr, qx0, qx1, qx2, qxs, 12) \
            HITR(accv, jb, foff, thr, qx0, qx1, qx2, qxs, 13) \
            HITR(accv, jb, foff, thr, qx0, qx1, qx2, qxs, 14) \
            HITR(accv, jb, foff, thr, qx0, qx1, qx2, qxs, 15) \
        }

    STAGE(c0, 0);
    __syncthreads();
    int cur = 0;
    for (int c = c0; c < c1; ++c) {
        if (c + 1 < c1) STAGE(c + 1, cur ^ 1);
#pragma unroll
        for (int tp = 0; tp < CH / 32; ++tp) {
            const s16x8 pA = *(const s16x8*)&lds[cur][ldsb + tp * 32];
            const int jb = c * CH + tp * 32;
            const f32x16 a0 = __builtin_amdgcn_mfma_f32_32x32x16_bf16(pA, qfr0, zf, 0, 0, 0);
            HIT(a0, jb, 0, thr0, qa0, qa1, qa2, qas)
            const f32x16 a1 = __builtin_amdgcn_mfma_f32_32x32x16_bf16(pA, qfr1, zf, 0, 0, 0);
            HIT(a1, jb, 32, thr1, qb0, qb1, qb2, qbs)
        }
        __syncthreads();
        cur ^= 1;
    }
#undef HIT
#undef HITR

    __syncthreads();
    {
        const unsigned long long m = keys[tid];
        const size_t gq = (size_t)dir * BN + bofs + (size_t)xblk * QPB + tid;
        if (ksplit == 2) {
            atomicMin(&gkeys[gq], m);          // merge the two k-halves
        } else {
            const uint32_t k32 = (uint32_t)(m >> 32);
            const size_t q = (size_t)bofs + (size_t)xblk * QPB + tid;
            out[(size_t)dir * BN + q]       = dec32(k32);
            out[(size_t)(2 + dir) * BN + q] = (float)(uint32_t)(m & 0xFFFFFFFFu);
        }
    }
}

// ---- final: gkeys -> (dist, idx) ----
__global__ __launch_bounds__(256) void writeout_k(
    const unsigned long long* __restrict__ gkeys, float* __restrict__ out)
{
    const size_t i = (size_t)blockIdx.x * 256 + threadIdx.x;   // 0..2*BN-1
    const unsigned long long m = gkeys[i];
    const int dir = (int)(i / BN);
    const size_t q = i - (size_t)dir * BN;
    out[(size_t)dir * BN + q]       = dec32((uint32_t)(m >> 32));
    out[(size_t)(2 + dir) * BN + q] = (float)(uint32_t)(m & 0xFFFFFFFFu);
}

extern "C" void kernel_launch(void* const* d_in, const int* in_sizes, int n_in,
                              void* d_out, int out_size, void* d_ws, size_t ws_size,
                              hipStream_t stream) {
    const float* xyz1 = (const float*)d_in[0];
    const float* xyz2 = (const float*)d_in[1];
    float* out = (float*)d_out;

    uint4*    encA  = (uint4*)d_ws;                        // 4 MiB
    uint4*    encB  = encA + (size_t)BN * 2;               // 4 MiB
    uint32_t* mkey  = (uint32_t*)(encB + (size_t)BN * 2);  // 1 MiB
    unsigned long long* gkeys = (unsigned long long*)(mkey + (size_t)2 * BN); // 2 MiB

    enc_kernel<<<BN / 256, 256, 0, stream>>>(xyz2, encA);
    enc_kernel<<<BN / 256, 256, 0, stream>>>(xyz1, encB);

    if (ws_size >= (size_t)11 * 1024 * 1024) {
        // k-split path: memset mkey (1MB) + gkeys (2MB) to all-ones = +inf keys
        hipMemsetAsync(mkey, 0xFF, (size_t)3 * 1024 * 1024, stream);
        nn_sweep1<<<2048, 256, 0, stream>>>(xyz1, xyz2, encA, encB, mkey, 2);
        nn_sweep2<<<2048, 256, 0, stream>>>(xyz1, xyz2, encA, encB, mkey, gkeys, out, 2);
        writeout_k<<<(2 * BN) / 256, 256, 0, stream>>>(gkeys, out);
    } else {
        hipMemsetAsync(mkey, 0xFF, (size_t)1024 * 1024, stream);
        nn_sweep1<<<1024, 256, 0, stream>>>(xyz1, xyz2, encA, encB, mkey, 1);
        nn_sweep2<<<1024, 256, 0, stream>>>(xyz1, xyz2, encA, encB, mkey, nullptr, out, 1);
    }
}